// Round 6
// baseline (299.273 us; speedup 1.0000x reference)
//
#include <hip/hip_runtime.h>
#include <hip/hip_bf16.h>

#define D_MODEL 768
#define D_HIDDEN 2048
#define NHEADS 12
#define BATCH 4
#define SEQ 128
#define MROWS (BATCH*SEQ)                      // 512
#define SCORE_ELEMS (BATCH*NHEADS*SEQ*SEQ)     // 786432
#define REG_OFF SCORE_ELEMS
#define FIRES_OFF (SCORE_ELEMS + 1)
#define TRIGMAX 8192
#define NFIRES_BLOCKS 1024

typedef __attribute__((ext_vector_type(8))) short bf16x8;
typedef __attribute__((ext_vector_type(4))) float f32x4;

static __device__ __forceinline__ unsigned short f2bf(float f) {
    union { float f; unsigned u; } v; v.f = f;
    unsigned u = v.u;
    return (unsigned short)((u + 0x7FFFu + ((u >> 16) & 1u)) >> 16);  // RNE
}

// ---------------------------------------------------------------------------
// Kernel 0: zero the trigger counter.
// ---------------------------------------------------------------------------
__global__ void init_kernel(unsigned* __restrict__ trigc) {
    if (threadIdx.x == 0) *trigc = 0u;
}

// ---------------------------------------------------------------------------
// Kernel 1: fused encoder GEMM  out = relu(x @ W + b) for Q (z=0) and K (z=1).
// M=512, N=2048, K=768. BM=64, BN=64, BK=16, fp32 accum. Grid (32,8,2)=512
// -> 2 blocks/CU, 2 waves/SIMD (was 1: latency fully exposed).
// Near-zero preacts (|pre| < 3e-4) go to a trigger list; fix_kernel recomputes
// them in fp64 so fires signs match the true value.
// ---------------------------------------------------------------------------
__global__ __launch_bounds__(256) void enc_kernel(
    const float* __restrict__ x,
    const float* __restrict__ WQ, const float* __restrict__ WK,
    const float* __restrict__ bQ, const float* __restrict__ bK,
    float* __restrict__ qbuf, float* __restrict__ kbuf,
    unsigned* __restrict__ trigc, unsigned* __restrict__ trig, int cap)
{
    __shared__ float xs[64][16];
    __shared__ float wt[16][64];
    const int bufid = blockIdx.z;
    const float* W    = bufid ? WK : WQ;
    const float* bias = bufid ? bK : bQ;
    float* outbuf     = bufid ? kbuf : qbuf;

    const int t  = threadIdx.x;
    const int m0 = blockIdx.y * 64;
    const int n0 = blockIdx.x * 64;
    const int rg = t >> 4;    // 0..15 -> 4 rows each
    const int cg = t & 15;    // 0..15 -> 4 cols each

    float acc[4][4];
    #pragma unroll
    for (int i = 0; i < 4; ++i)
        #pragma unroll
        for (int c = 0; c < 4; ++c) acc[i][c] = 0.f;

    for (int kk = 0; kk < D_MODEL; kk += 16) {
        #pragma unroll
        for (int u = 0; u < 4; ++u) {
            int idx = t + 256 * u; int r = idx >> 4, j = idx & 15;
            xs[r][j] = x[(size_t)(m0 + r) * D_MODEL + kk + j];
        }
        #pragma unroll
        for (int u = 0; u < 4; ++u) {
            int idx = t + 256 * u; int r = idx >> 6, c = idx & 63;
            wt[r][c] = W[(size_t)(kk + r) * D_HIDDEN + n0 + c];
        }
        __syncthreads();
        #pragma unroll
        for (int j = 0; j < 16; ++j) {
            float a[4];
            #pragma unroll
            for (int i = 0; i < 4; ++i) a[i] = xs[rg * 4 + i][j];
            const float4 wv = *reinterpret_cast<const float4*>(&wt[j][cg * 4]);
            const float wr[4] = {wv.x, wv.y, wv.z, wv.w};
            #pragma unroll
            for (int i = 0; i < 4; ++i)
                #pragma unroll
                for (int c = 0; c < 4; ++c) acc[i][c] = fmaf(a[i], wr[c], acc[i][c]);
        }
        __syncthreads();
    }

    #pragma unroll
    for (int i = 0; i < 4; ++i) {
        const int m = m0 + rg * 4 + i;
        const int hb = n0 + cg * 4;
        f32x4 ov;
        #pragma unroll
        for (int c = 0; c < 4; ++c) {
            const int h = hb + c;
            float pre = acc[i][c] + bias[h];
            if (fabsf(pre) < 3e-4f) {
                if (cap > 0) {
                    unsigned idx = atomicAdd(trigc, 1u);
                    if ((int)idx < cap)
                        trig[idx] = ((unsigned)bufid << 20) | ((unsigned)m << 11) | (unsigned)h;
                } else {
                    const float* xr = x + (size_t)m * D_MODEL;
                    const float* wc = W + h;
                    double s = (double)bias[h];
                    for (int dd = 0; dd < D_MODEL; ++dd)
                        s += (double)xr[dd] * (double)wc[(size_t)dd * D_HIDDEN];
                    pre = (float)s;
                }
            }
            ov[c] = fmaxf(pre, 0.f);
        }
        *reinterpret_cast<f32x4*>(outbuf + (size_t)m * D_HIDDEN + hb) = ov;
    }
}

// ---------------------------------------------------------------------------
// Kernel 1b: fp64 fix for near-zero preacts. One block per trigger (strided).
// ---------------------------------------------------------------------------
__global__ __launch_bounds__(256) void fix_kernel(
    const float* __restrict__ x,
    const float* __restrict__ WQ, const float* __restrict__ WK,
    const float* __restrict__ bQ, const float* __restrict__ bK,
    float* __restrict__ qbuf, float* __restrict__ kbuf,
    const unsigned* __restrict__ trigc, const unsigned* __restrict__ trig,
    int cap)
{
    __shared__ double red[4];
    const unsigned n = min(*trigc, (unsigned)cap);
    for (unsigned i = blockIdx.x; i < n; i += gridDim.x) {
        const unsigned e = trig[i];
        const int h = e & 2047, m = (e >> 11) & 511, bid = (int)(e >> 20);
        const float* W  = bid ? WK : WQ;
        const float* bb = bid ? bK : bQ;
        float* ob       = bid ? kbuf : qbuf;
        const float* xr = x + (size_t)m * D_MODEL;
        double s = 0.0;
        for (int dd = threadIdx.x; dd < D_MODEL; dd += 256)
            s += (double)xr[dd] * (double)W[(size_t)dd * D_HIDDEN + h];
        #pragma unroll
        for (int off = 32; off > 0; off >>= 1) s += __shfl_down(s, off);
        if ((threadIdx.x & 63) == 0) red[threadIdx.x >> 6] = s;
        __syncthreads();
        if (threadIdx.x == 0) {
            double tot = red[0] + red[1] + red[2] + red[3] + (double)bb[h];
            ob[(size_t)m * D_HIDDEN + h] = fmaxf((float)tot, 0.f);
        }
        __syncthreads();
    }
}

// ---------------------------------------------------------------------------
// Kernel 2: fires + reg partials. Block = 4 q-rows x 16 k-rows, SW-pipelined:
// k-row (k0+1) is PREFETCHED into the alternate named buffer BEFORE the store
// burst of k0, so every load-wait targets loads OLDER than pending stores
// (vmcnt retires in issue order -> waits never drain the store stream).
// grid = 4b * 32qc * 8kc = 1024 blocks (4/CU, 4 waves/SIMD).
// Edge elements (h=0,1,2,2047 per row) handled in one pass at block end.
// ---------------------------------------------------------------------------
__device__ __forceinline__ void load_krow(const float* __restrict__ kr,
                                          int h1, int h2, bool has2,
                                          float kv1[4], float kv2[4]) {
    #pragma unroll
    for (int e = 0; e < 4; ++e) kv1[e] = kr[h1 + e];
    #pragma unroll
    for (int e = 0; e < 4; ++e) kv2[e] = has2 ? kr[h2 + e] : 0.f;
}

__device__ __forceinline__ void fires_step(
    const float qv1[4][4], const float qv2[4][4],
    const float kv1[4], const float kv2[4], bool has2,
    float* __restrict__ out, size_t qrow0, int kcol, int h1, int h2,
    float racc[4])
{
    #pragma unroll
    for (int r = 0; r < 4; ++r) {
        float* orow = out + FIRES_OFF +
            ((qrow0 + r) * SEQ + (size_t)kcol) * D_HIDDEN;
        const float p0 = qv1[r][0] * kv1[0];
        const float p1 = qv1[r][1] * kv1[1];
        const float p2 = qv1[r][2] * kv1[2];
        const float p3 = qv1[r][3] * kv1[3];
        f32x4 f1;
        f1.x = (p0 > 0.f) ? 1.f : 0.f;
        f1.y = (p1 > 0.f) ? 1.f : 0.f;
        f1.z = (p2 > 0.f) ? 1.f : 0.f;
        f1.w = (p3 > 0.f) ? 1.f : 0.f;
        *reinterpret_cast<f32x4*>(orow + h1) = f1;
        float s = (sqrtf(p0 + 1e-6f) + sqrtf(p1 + 1e-6f))
                + (sqrtf(p2 + 1e-6f) + sqrtf(p3 + 1e-6f));
        if (has2) {
            const float p4 = qv2[r][0] * kv2[0];
            const float p5 = qv2[r][1] * kv2[1];
            const float p6 = qv2[r][2] * kv2[2];
            const float p7 = qv2[r][3] * kv2[3];
            f32x4 f2;
            f2.x = (p4 > 0.f) ? 1.f : 0.f;
            f2.y = (p5 > 0.f) ? 1.f : 0.f;
            f2.z = (p6 > 0.f) ? 1.f : 0.f;
            f2.w = (p7 > 0.f) ? 1.f : 0.f;
            *reinterpret_cast<f32x4*>(orow + h2) = f2;
            s += (sqrtf(p4 + 1e-6f) + sqrtf(p5 + 1e-6f))
               + (sqrtf(p6 + 1e-6f) + sqrtf(p7 + 1e-6f));
        }
        racc[r] += s;
    }
}

__global__ __launch_bounds__(256) void fires_kernel(
    const float* __restrict__ qbuf, const float* __restrict__ kbuf,
    float* __restrict__ out, float* __restrict__ partial)
{
    const int t  = threadIdx.x;
    const int bi = blockIdx.x;
    const int kc = bi & 7;             // 8 chunks of 16 k-rows
    const int qc = (bi >> 3) & 31;     // 32 chunks of 4 q-rows
    const int b  = bi >> 8;

    const int h1 = 3 + 4 * t;          // h = 3..1026
    const int h2 = h1 + 1024;          // h = 1027..2046 (t<255)
    const bool has2 = (t < 255);

    const size_t qrow0 = (size_t)(b * SEQ + qc * 4);
    float qv1[4][4], qv2[4][4];
    #pragma unroll
    for (int r = 0; r < 4; ++r) {
        const float* qr_ = qbuf + (qrow0 + r) * D_HIDDEN;
        #pragma unroll
        for (int e = 0; e < 4; ++e) qv1[r][e] = qr_[h1 + e];
        #pragma unroll
        for (int e = 0; e < 4; ++e) qv2[r][e] = has2 ? qr_[h2 + e] : 0.f;
    }

    float racc[4] = {0.f, 0.f, 0.f, 0.f};
    const float* kbase = kbuf + (size_t)(b * SEQ + kc * 16) * D_HIDDEN;
    const int kcol0 = kc * 16;

    float kvA1[4], kvA2[4], kvB1[4], kvB2[4];
    load_krow(kbase, h1, h2, has2, kvA1, kvA2);

    #pragma unroll 1
    for (int k0 = 0; k0 < 16; k0 += 2) {
        // prefetch k0+1 BEFORE storing k0 (loads older than stores)
        load_krow(kbase + (size_t)(k0 + 1) * D_HIDDEN, h1, h2, has2, kvB1, kvB2);
        fires_step(qv1, qv2, kvA1, kvA2, has2, out, qrow0, kcol0 + k0, h1, h2, racc);
        if (k0 + 2 < 16)
            load_krow(kbase + (size_t)(k0 + 2) * D_HIDDEN, h1, h2, has2, kvA1, kvA2);
        fires_step(qv1, qv2, kvB1, kvB2, has2, out, qrow0, kcol0 + k0 + 1, h1, h2, racc);
    }

    // edge pass: 4 qrows x 16 krows x 4 elems = 256 -> one per thread
    float redge;
    {
        const int r  = t >> 6;                    // q-row 0..3
        const int kr = (t >> 2) & 15;             // k-row 0..15
        const int he = ((t & 3) < 3) ? (t & 3) : 2047;
        const float qe = qbuf[(qrow0 + r) * D_HIDDEN + he];
        const float ke = kbase[(size_t)kr * D_HIDDEN + he];
        const float pe = qe * ke;
        float* orow = out + FIRES_OFF +
            ((qrow0 + r) * SEQ + (size_t)(kcol0 + kr)) * D_HIDDEN;
        orow[he] = (pe > 0.f) ? 1.f : 0.f;
        redge = sqrtf(pe + 1e-6f);
    }

    float rt = ((racc[0] + racc[1]) + (racc[2] + racc[3])) + redge;
    #pragma unroll
    for (int off = 32; off > 0; off >>= 1) rt += __shfl_down(rt, off);
    __shared__ float rs[4];
    if ((t & 63) == 0) rs[t >> 6] = rt;
    __syncthreads();
    if (t == 0) partial[bi] = (rs[0] + rs[1]) + (rs[2] + rs[3]);
}

// ---------------------------------------------------------------------------
// Kernel 2b: deterministic fixed-order reduction of block partials -> reg_loss.
// ---------------------------------------------------------------------------
__global__ __launch_bounds__(256) void reduce_kernel(
    const float* __restrict__ partial, float* __restrict__ reg)
{
    __shared__ float rs[4];
    const int t = threadIdx.x;
    float s = (partial[t] + partial[t + 256]) + (partial[t + 512] + partial[t + 768]);
    #pragma unroll
    for (int off = 32; off > 0; off >>= 1) s += __shfl_down(s, off);
    if ((t & 63) == 0) rs[t >> 6] = s;
    __syncthreads();
    if (t == 0) *reg = ((rs[0] + rs[1]) + (rs[2] + rs[3])) * 1e-3f;
}

// ---------------------------------------------------------------------------
// Kernel 3: score via bf16 MFMA. For each (b,n): C[q,k] = (q .* Wdec[:,n]) @ K^T
// ---------------------------------------------------------------------------
__global__ __launch_bounds__(256) void score_kernel(
    const float* __restrict__ qbuf, const float* __restrict__ kbuf,
    const float* __restrict__ Wdec, const float* __restrict__ bdec,
    float* __restrict__ out)
{
    __shared__ float wcol[D_HIDDEN];
    const int t   = threadIdx.x;
    const int bi  = blockIdx.x;
    const int sub = bi & 3;
    const int pr  = bi >> 2;
    const int n   = pr % NHEADS;
    const int b   = pr / NHEADS;

    for (int idx = t; idx < D_HIDDEN; idx += 256)
        wcol[idx] = Wdec[(size_t)idx * NHEADS + n];
    __syncthreads();

    const int q0   = (sub >> 1) * 64;
    const int k0   = (sub & 1) * 64;
    const int w    = t >> 6;
    const int lane = t & 63;
    const int lrow = lane & 15;
    const int koff = (lane >> 4) * 8;
    const int qw   = q0 + (w >> 1) * 32;
    const int kw   = k0 + (w & 1) * 32;

    f32x4 acc[2][2];
    #pragma unroll
    for (int i = 0; i < 2; ++i)
        #pragma unroll
        for (int j = 0; j < 2; ++j) { f32x4 z = {0.f, 0.f, 0.f, 0.f}; acc[i][j] = z; }

    const float* qb = qbuf + (size_t)b * SEQ * D_HIDDEN;
    const float* kb = kbuf + (size_t)b * SEQ * D_HIDDEN;

    for (int kk = 0; kk < D_HIDDEN; kk += 32) {
        const int h0 = kk + koff;
        float wv[8];
        #pragma unroll
        for (int i = 0; i < 8; ++i) wv[i] = wcol[h0 + i];

        bf16x8 afrag[2], bfrag[2];
        #pragma unroll
        for (int fi = 0; fi < 2; ++fi) {
            const float* qp = qb + (size_t)(qw + fi * 16 + lrow) * D_HIDDEN + h0;
            const float4 q1 = *reinterpret_cast<const float4*>(qp);
            const float4 q2 = *reinterpret_cast<const float4*>(qp + 4);
            const float qf[8] = {q1.x, q1.y, q1.z, q1.w, q2.x, q2.y, q2.z, q2.w};
            #pragma unroll
            for (int i = 0; i < 8; ++i) afrag[fi][i] = (short)f2bf(qf[i] * wv[i]);
        }
        #pragma unroll
        for (int fj = 0; fj < 2; ++fj) {
            const float* kp = kb + (size_t)(kw + fj * 16 + lrow) * D_HIDDEN + h0;
            const float4 k1 = *reinterpret_cast<const float4*>(kp);
            const float4 k2 = *reinterpret_cast<const float4*>(kp + 4);
            const float kf[8] = {k1.x, k1.y, k1.z, k1.w, k2.x, k2.y, k2.z, k2.w};
            #pragma unroll
            for (int i = 0; i < 8; ++i) bfrag[fj][i] = (short)f2bf(kf[i]);
        }
        #pragma unroll
        for (int fi = 0; fi < 2; ++fi)
            #pragma unroll
            for (int fj = 0; fj < 2; ++fj)
                acc[fi][fj] = __builtin_amdgcn_mfma_f32_16x16x32_bf16(
                    afrag[fi], bfrag[fj], acc[fi][fj], 0, 0, 0);
    }

    const float bd   = bdec[n];
    const int   outb = (b * NHEADS + n) * SEQ * SEQ;
    #pragma unroll
    for (int fi = 0; fi < 2; ++fi)
        #pragma unroll
        for (int fj = 0; fj < 2; ++fj)
            #pragma unroll
            for (int j = 0; j < 4; ++j) {
                const int row = qw + fi * 16 + (lane >> 4) * 4 + j;
                const int col = kw + fj * 16 + (lane & 15);
                out[outb + row * SEQ + col] = acc[fi][fj][j] * 0.125f + bd;
            }
}

// ---------------------------------------------------------------------------
extern "C" void kernel_launch(void* const* d_in, const int* in_sizes, int n_in,
                              void* d_out, int out_size, void* d_ws, size_t ws_size,
                              hipStream_t stream) {
    const float* x  = (const float*)d_in[0];
    const float* WQ = (const float*)d_in[1];
    const float* WK = (const float*)d_in[2];
    const float* bQ = (const float*)d_in[3];
    const float* bK = (const float*)d_in[4];
    const float* Wd = (const float*)d_in[5];
    const float* bd = (const float*)d_in[6];
    float* out  = (float*)d_out;
    float* qbuf = (float*)d_ws;                                // 4 MB
    float* kbuf = qbuf + (size_t)MROWS * D_HIDDEN;             // 4 MB
    float* partial = kbuf + (size_t)MROWS * D_HIDDEN;          // 1024 floats
    unsigned* trigc = (unsigned*)(partial + NFIRES_BLOCKS);
    unsigned* trig  = trigc + 1;
    const size_t need = (size_t)8 * 1024 * 1024 + NFIRES_BLOCKS * 4 + 4 + (size_t)TRIGMAX * 4;
    const int cap = (ws_size >= need) ? TRIGMAX : 0;

    dim3 b256(256);

    if (cap > 0) init_kernel<<<dim3(1), dim3(64), 0, stream>>>(trigc);

    enc_kernel<<<dim3(D_HIDDEN / 64, MROWS / 64, 2), b256, 0, stream>>>(
        x, WQ, WK, bQ, bK, qbuf, kbuf, trigc, trig, cap);
    if (cap > 0)
        fix_kernel<<<dim3(128), b256, 0, stream>>>(x, WQ, WK, bQ, bK, qbuf, kbuf, trigc, trig, cap);

    score_kernel<<<dim3(BATCH * NHEADS * 4), b256, 0, stream>>>(qbuf, kbuf, Wd, bd, out);
    fires_kernel<<<dim3(NFIRES_BLOCKS), b256, 0, stream>>>(qbuf, kbuf, out, partial);
    reduce_kernel<<<dim3(1), b256, 0, stream>>>(partial, out + REG_OFF);
}

// Round 7
// 268.966 us; speedup vs baseline: 1.1127x; 1.1127x over previous
//
#include <hip/hip_runtime.h>
#include <hip/hip_bf16.h>

#define D_MODEL 768
#define D_HIDDEN 2048
#define NHEADS 12
#define BATCH 4
#define SEQ 128
#define MROWS (BATCH*SEQ)                      // 512
#define SCORE_ELEMS (BATCH*NHEADS*SEQ*SEQ)     // 786432
#define REG_OFF SCORE_ELEMS
#define FIRES_OFF (SCORE_ELEMS + 1)
#define TRIGMAX 8192
#define NFIRES_BLOCKS 2048

typedef __attribute__((ext_vector_type(8))) short bf16x8;
typedef __attribute__((ext_vector_type(4))) float f32x4;

static __device__ __forceinline__ unsigned short f2bf(float f) {
    union { float f; unsigned u; } v; v.f = f;
    unsigned u = v.u;
    return (unsigned short)((u + 0x7FFFu + ((u >> 16) & 1u)) >> 16);  // RNE
}

// ---------------------------------------------------------------------------
// Kernel 0: zero the trigger counter.
// ---------------------------------------------------------------------------
__global__ void init_kernel(unsigned* __restrict__ trigc) {
    if (threadIdx.x == 0) *trigc = 0u;
}

// ---------------------------------------------------------------------------
// Kernel 1: fused encoder GEMM  out = relu(x @ W + b) for Q (z=0) and K (z=1).
// M=512, N=2048, K=768. BM=64, BN=128, BK=16, fp32 accum. Grid (16,8,2)=256.
// Near-zero preacts (|pre| < 3e-4) go to a trigger list; fix_kernel recomputes
// them in fp64 so fires signs match the true value.
// ---------------------------------------------------------------------------
__global__ __launch_bounds__(256) void enc_kernel(
    const float* __restrict__ x,
    const float* __restrict__ WQ, const float* __restrict__ WK,
    const float* __restrict__ bQ, const float* __restrict__ bK,
    float* __restrict__ qbuf, float* __restrict__ kbuf,
    unsigned* __restrict__ trigc, unsigned* __restrict__ trig, int cap)
{
    __shared__ float xs[64][16];
    __shared__ float wt[16][128];
    const int bufid = blockIdx.z;
    const float* W    = bufid ? WK : WQ;
    const float* bias = bufid ? bK : bQ;
    float* outbuf     = bufid ? kbuf : qbuf;

    const int t  = threadIdx.x;
    const int m0 = blockIdx.y * 64;
    const int n0 = blockIdx.x * 128;
    const int rg = t >> 5;    // 0..7  -> 8 rows each
    const int cg = t & 31;    // 0..31 -> 4 cols each

    float acc[8][4];
    #pragma unroll
    for (int i = 0; i < 8; ++i)
        #pragma unroll
        for (int c = 0; c < 4; ++c) acc[i][c] = 0.f;

    for (int kk = 0; kk < D_MODEL; kk += 16) {
        #pragma unroll
        for (int u = 0; u < 4; ++u) {
            int idx = t + 256 * u; int r = idx >> 4, j = idx & 15;
            xs[r][j] = x[(size_t)(m0 + r) * D_MODEL + kk + j];
        }
        #pragma unroll
        for (int u = 0; u < 8; ++u) {
            int idx = t + 256 * u; int r = idx >> 7, c = idx & 127;
            wt[r][c] = W[(size_t)(kk + r) * D_HIDDEN + n0 + c];
        }
        __syncthreads();
        #pragma unroll
        for (int j = 0; j < 16; ++j) {
            float a[8];
            #pragma unroll
            for (int i = 0; i < 8; ++i) a[i] = xs[rg * 8 + i][j];
            const float4 wv = *reinterpret_cast<const float4*>(&wt[j][cg * 4]);
            const float wr[4] = {wv.x, wv.y, wv.z, wv.w};
            #pragma unroll
            for (int i = 0; i < 8; ++i)
                #pragma unroll
                for (int c = 0; c < 4; ++c) acc[i][c] = fmaf(a[i], wr[c], acc[i][c]);
        }
        __syncthreads();
    }

    #pragma unroll
    for (int i = 0; i < 8; ++i) {
        const int m = m0 + rg * 8 + i;
        const int hb = n0 + cg * 4;
        f32x4 ov;
        #pragma unroll
        for (int c = 0; c < 4; ++c) {
            const int h = hb + c;
            float pre = acc[i][c] + bias[h];
            if (fabsf(pre) < 3e-4f) {
                if (cap > 0) {
                    unsigned idx = atomicAdd(trigc, 1u);
                    if ((int)idx < cap)
                        trig[idx] = ((unsigned)bufid << 20) | ((unsigned)m << 11) | (unsigned)h;
                } else {
                    const float* xr = x + (size_t)m * D_MODEL;
                    const float* wc = W + h;
                    double s = (double)bias[h];
                    for (int dd = 0; dd < D_MODEL; ++dd)
                        s += (double)xr[dd] * (double)wc[(size_t)dd * D_HIDDEN];
                    pre = (float)s;
                }
            }
            ov[c] = fmaxf(pre, 0.f);
        }
        *reinterpret_cast<f32x4*>(outbuf + (size_t)m * D_HIDDEN + hb) = ov;
    }
}

// ---------------------------------------------------------------------------
// Kernel 1b: fp64 fix for near-zero preacts. One block per trigger (strided).
// ---------------------------------------------------------------------------
__global__ __launch_bounds__(256) void fix_kernel(
    const float* __restrict__ x,
    const float* __restrict__ WQ, const float* __restrict__ WK,
    const float* __restrict__ bQ, const float* __restrict__ bK,
    float* __restrict__ qbuf, float* __restrict__ kbuf,
    const unsigned* __restrict__ trigc, const unsigned* __restrict__ trig,
    int cap)
{
    __shared__ double red[4];
    const unsigned n = min(*trigc, (unsigned)cap);
    for (unsigned i = blockIdx.x; i < n; i += gridDim.x) {
        const unsigned e = trig[i];
        const int h = e & 2047, m = (e >> 11) & 511, bid = (int)(e >> 20);
        const float* W  = bid ? WK : WQ;
        const float* bb = bid ? bK : bQ;
        float* ob       = bid ? kbuf : qbuf;
        const float* xr = x + (size_t)m * D_MODEL;
        double s = 0.0;
        for (int dd = threadIdx.x; dd < D_MODEL; dd += 256)
            s += (double)xr[dd] * (double)W[(size_t)dd * D_HIDDEN + h];
        #pragma unroll
        for (int off = 32; off > 0; off >>= 1) s += __shfl_down(s, off);
        if ((threadIdx.x & 63) == 0) red[threadIdx.x >> 6] = s;
        __syncthreads();
        if (threadIdx.x == 0) {
            double tot = red[0] + red[1] + red[2] + red[3] + (double)bb[h];
            ob[(size_t)m * D_HIDDEN + h] = fmaxf((float)tot, 0.f);
        }
        __syncthreads();
    }
}

// ---------------------------------------------------------------------------
// Kernel 2: fires + reg partials, LDS-staged ablation of the load path.
// Block = 4 q-rows x 8 k-rows. The 8 k-rows (64 KB) are staged into LDS ONCE
// (coalesced float4), so the hot loop has ZERO global loads: LDS reads +
// global stores + VALU only. If load-latency-under-store-pressure was the
// limiter, this removes it. 2 blocks/CU (64KB LDS), grid = 4b*32qc*16kc=2048.
// Fires row base == 1 mod 4: h in [3,2046] via aligned f32x4 global stores;
// edges {0,1,2,2047} in one 128-thread pass at block end (k from LDS).
// ---------------------------------------------------------------------------
__global__ __launch_bounds__(256) void fires_kernel(
    const float* __restrict__ qbuf, const float* __restrict__ kbuf,
    float* __restrict__ out, float* __restrict__ partial)
{
    __shared__ float klds[8][D_HIDDEN];        // 64 KB

    const int t  = threadIdx.x;
    const int bi = blockIdx.x;
    const int kc = bi & 15;            // 16 chunks of 8 k-rows
    const int qc = (bi >> 4) & 31;     // 32 chunks of 4 q-rows
    const int b  = bi >> 9;

    const int h1 = 3 + 4 * t;          // h = 3..1026
    const int h2 = h1 + 1024;          // h = 1027..2046 (t<255)
    const bool has2 = (t < 255);

    const size_t qrow0 = (size_t)(b * SEQ + qc * 4);
    const float* kbase = kbuf + (size_t)(b * SEQ + kc * 8) * D_HIDDEN;
    const int kcol0 = kc * 8;

    // stage 8 k-rows into LDS: 4096 float4s, 16 per thread, coalesced+aligned
    #pragma unroll
    for (int u = 0; u < 16; ++u) {
        const int fid = t + 256 * u;
        const int row = fid >> 9;
        const int c4  = (fid & 511) * 4;
        *reinterpret_cast<f32x4*>(&klds[row][c4]) =
            *reinterpret_cast<const f32x4*>(kbase + (size_t)row * D_HIDDEN + c4);
    }

    // q slices in registers (overlaps staging)
    float qv1[4][4], qv2[4][4];
    #pragma unroll
    for (int r = 0; r < 4; ++r) {
        const float* qr_ = qbuf + (qrow0 + r) * D_HIDDEN;
        #pragma unroll
        for (int e = 0; e < 4; ++e) qv1[r][e] = qr_[h1 + e];
        #pragma unroll
        for (int e = 0; e < 4; ++e) qv2[r][e] = has2 ? qr_[h2 + e] : 0.f;
    }
    __syncthreads();

    float racc[4] = {0.f, 0.f, 0.f, 0.f};

    #pragma unroll 1
    for (int k0 = 0; k0 < 8; ++k0) {
        float kv1[4], kv2[4];
        #pragma unroll
        for (int e = 0; e < 4; ++e) kv1[e] = klds[k0][h1 + e];
        #pragma unroll
        for (int e = 0; e < 4; ++e) kv2[e] = has2 ? klds[k0][h2 + e] : 0.f;
        const int kcol = kcol0 + k0;

        #pragma unroll
        for (int r = 0; r < 4; ++r) {
            float* orow = out + FIRES_OFF +
                ((qrow0 + r) * SEQ + (size_t)kcol) * D_HIDDEN;
            const float p0 = qv1[r][0] * kv1[0];
            const float p1 = qv1[r][1] * kv1[1];
            const float p2 = qv1[r][2] * kv1[2];
            const float p3 = qv1[r][3] * kv1[3];
            f32x4 f1;
            f1.x = (p0 > 0.f) ? 1.f : 0.f;
            f1.y = (p1 > 0.f) ? 1.f : 0.f;
            f1.z = (p2 > 0.f) ? 1.f : 0.f;
            f1.w = (p3 > 0.f) ? 1.f : 0.f;
            *reinterpret_cast<f32x4*>(orow + h1) = f1;
            float s = (sqrtf(p0 + 1e-6f) + sqrtf(p1 + 1e-6f))
                    + (sqrtf(p2 + 1e-6f) + sqrtf(p3 + 1e-6f));
            if (has2) {
                const float p4 = qv2[r][0] * kv2[0];
                const float p5 = qv2[r][1] * kv2[1];
                const float p6 = qv2[r][2] * kv2[2];
                const float p7 = qv2[r][3] * kv2[3];
                f32x4 f2;
                f2.x = (p4 > 0.f) ? 1.f : 0.f;
                f2.y = (p5 > 0.f) ? 1.f : 0.f;
                f2.z = (p6 > 0.f) ? 1.f : 0.f;
                f2.w = (p7 > 0.f) ? 1.f : 0.f;
                *reinterpret_cast<f32x4*>(orow + h2) = f2;
                s += (sqrtf(p4 + 1e-6f) + sqrtf(p5 + 1e-6f))
                   + (sqrtf(p6 + 1e-6f) + sqrtf(p7 + 1e-6f));
            }
            racc[r] += s;
        }
    }

    // edge pass: 4 qrows x 8 krows x 4 elems = 128 -> threads t<128
    float redge = 0.f;
    if (t < 128) {
        const int r   = t >> 5;                   // q-row 0..3
        const int idx = t & 31;
        const int kr0 = idx >> 2;                 // k-row 0..7
        const int e   = idx & 3;
        const int he  = (e < 3) ? e : 2047;
        const float qe = qbuf[(qrow0 + r) * D_HIDDEN + he];
        const float ke = klds[kr0][he];
        const float pe = qe * ke;
        float* orow = out + FIRES_OFF +
            ((qrow0 + r) * SEQ + (size_t)(kcol0 + kr0)) * D_HIDDEN;
        orow[he] = (pe > 0.f) ? 1.f : 0.f;
        redge = sqrtf(pe + 1e-6f);
    }

    float rt = ((racc[0] + racc[1]) + (racc[2] + racc[3])) + redge;
    #pragma unroll
    for (int off = 32; off > 0; off >>= 1) rt += __shfl_down(rt, off);
    __shared__ float rs[4];
    if ((t & 63) == 0) rs[t >> 6] = rt;
    __syncthreads();
    if (t == 0) partial[bi] = (rs[0] + rs[1]) + (rs[2] + rs[3]);
}

// ---------------------------------------------------------------------------
// Kernel 2b: deterministic fixed-order reduction of block partials -> reg_loss.
// ---------------------------------------------------------------------------
__global__ __launch_bounds__(256) void reduce_kernel(
    const float* __restrict__ partial, float* __restrict__ reg)
{
    __shared__ float rs[4];
    const int t = threadIdx.x;
    float s = 0.f;
    #pragma unroll
    for (int u = 0; u < 8; ++u) s += partial[t + 256 * u];
    #pragma unroll
    for (int off = 32; off > 0; off >>= 1) s += __shfl_down(s, off);
    if ((t & 63) == 0) rs[t >> 6] = s;
    __syncthreads();
    if (t == 0) *reg = ((rs[0] + rs[1]) + (rs[2] + rs[3])) * 1e-3f;
}

// ---------------------------------------------------------------------------
// Kernel 3: score via bf16 MFMA, h-split across waves for occupancy.
// grid = 4b * 12n * 16 subtiles (32x32) = 768 blocks (3/CU).
// Each wave accumulates its 512-wide h-chunk; LDS reduction combines.
// ---------------------------------------------------------------------------
__global__ __launch_bounds__(256) void score_kernel(
    const float* __restrict__ qbuf, const float* __restrict__ kbuf,
    const float* __restrict__ Wdec, const float* __restrict__ bdec,
    float* __restrict__ out)
{
    __shared__ float wcol[D_HIDDEN];
    __shared__ float red[4][64][16];
    const int t   = threadIdx.x;
    const int bi  = blockIdx.x;
    const int sub = bi & 15;
    const int pr  = bi >> 4;
    const int n   = pr % NHEADS;
    const int b   = pr / NHEADS;

    for (int idx = t; idx < D_HIDDEN; idx += 256)
        wcol[idx] = Wdec[(size_t)idx * NHEADS + n];
    __syncthreads();

    const int qt   = (sub >> 2) * 32;
    const int kt   = (sub & 3) * 32;
    const int w    = t >> 6;
    const int lane = t & 63;
    const int lrow = lane & 15;
    const int koff = (lane >> 4) * 8;

    f32x4 acc[2][2];
    #pragma unroll
    for (int i = 0; i < 2; ++i)
        #pragma unroll
        for (int j = 0; j < 2; ++j) { f32x4 z = {0.f, 0.f, 0.f, 0.f}; acc[i][j] = z; }

    const float* qb = qbuf + (size_t)b * SEQ * D_HIDDEN;
    const float* kb = kbuf + (size_t)b * SEQ * D_HIDDEN;

    const int hlo = w * 512;
    for (int kk = hlo; kk < hlo + 512; kk += 32) {
        const int h0 = kk + koff;
        float wv[8];
        #pragma unroll
        for (int i = 0; i < 8; ++i) wv[i] = wcol[h0 + i];

        bf16x8 afrag[2], bfrag[2];
        #pragma unroll
        for (int fi = 0; fi < 2; ++fi) {
            const float* qp = qb + (size_t)(qt + fi * 16 + lrow) * D_HIDDEN + h0;
            const float4 q1 = *reinterpret_cast<const float4*>(qp);
            const float4 q2 = *reinterpret_cast<const float4*>(qp + 4);
            const float qf[8] = {q1.x, q1.y, q1.z, q1.w, q2.x, q2.y, q2.z, q2.w};
            #pragma unroll
            for (int i = 0; i < 8; ++i) afrag[fi][i] = (short)f2bf(qf[i] * wv[i]);
        }
        #pragma unroll
        for (int fj = 0; fj < 2; ++fj) {
            const float* kp = kb + (size_t)(kt + fj * 16 + lrow) * D_HIDDEN + h0;
            const float4 k1 = *reinterpret_cast<const float4*>(kp);
            const float4 k2 = *reinterpret_cast<const float4*>(kp + 4);
            const float kf[8] = {k1.x, k1.y, k1.z, k1.w, k2.x, k2.y, k2.z, k2.w};
            #pragma unroll
            for (int i = 0; i < 8; ++i) bfrag[fj][i] = (short)f2bf(kf[i]);
        }
        #pragma unroll
        for (int fi = 0; fi < 2; ++fi)
            #pragma unroll
            for (int fj = 0; fj < 2; ++fj)
                acc[fi][fj] = __builtin_amdgcn_mfma_f32_16x16x32_bf16(
                    afrag[fi], bfrag[fj], acc[fi][fj], 0, 0, 0);
    }

    #pragma unroll
    for (int fi = 0; fi < 2; ++fi)
        #pragma unroll
        for (int fj = 0; fj < 2; ++fj)
            #pragma unroll
            for (int j = 0; j < 4; ++j)
                red[w][lane][fi * 8 + fj * 4 + j] = acc[fi][fj][j];
    __syncthreads();

    const float bd   = bdec[n];
    const int   outb = (b * NHEADS + n) * SEQ * SEQ;
    #pragma unroll
    for (int u = 0; u < 4; ++u) {
        const int j = w * 4 + u;
        const float s = (red[0][lane][j] + red[1][lane][j])
                      + (red[2][lane][j] + red[3][lane][j]);
        const int fi = j >> 3, fj = (j >> 2) & 1, jj = j & 3;
        const int row = qt + fi * 16 + (lane >> 4) * 4 + jj;
        const int col = kt + fj * 16 + (lane & 15);
        out[outb + row * SEQ + col] = s * 0.125f + bd;
    }
}

// ---------------------------------------------------------------------------
extern "C" void kernel_launch(void* const* d_in, const int* in_sizes, int n_in,
                              void* d_out, int out_size, void* d_ws, size_t ws_size,
                              hipStream_t stream) {
    const float* x  = (const float*)d_in[0];
    const float* WQ = (const float*)d_in[1];
    const float* WK = (const float*)d_in[2];
    const float* bQ = (const float*)d_in[3];
    const float* bK = (const float*)d_in[4];
    const float* Wd = (const float*)d_in[5];
    const float* bd = (const float*)d_in[6];
    float* out  = (float*)d_out;
    float* qbuf = (float*)d_ws;                                // 4 MB
    float* kbuf = qbuf + (size_t)MROWS * D_HIDDEN;             // 4 MB
    float* partial = kbuf + (size_t)MROWS * D_HIDDEN;          // 2048 floats
    unsigned* trigc = (unsigned*)(partial + NFIRES_BLOCKS);
    unsigned* trig  = trigc + 1;
    const size_t need = (size_t)8 * 1024 * 1024 + NFIRES_BLOCKS * 4 + 4 + (size_t)TRIGMAX * 4;
    const int cap = (ws_size >= need) ? TRIGMAX : 0;

    dim3 b256(256);

    if (cap > 0) init_kernel<<<dim3(1), dim3(64), 0, stream>>>(trigc);

    enc_kernel<<<dim3(D_HIDDEN / 128, MROWS / 64, 2), b256, 0, stream>>>(
        x, WQ, WK, bQ, bK, qbuf, kbuf, trigc, trig, cap);
    if (cap > 0)
        fix_kernel<<<dim3(128), b256, 0, stream>>>(x, WQ, WK, bQ, bK, qbuf, kbuf, trigc, trig, cap);

    score_kernel<<<dim3(BATCH * NHEADS * 16), b256, 0, stream>>>(qbuf, kbuf, Wd, bd, out);
    fires_kernel<<<dim3(NFIRES_BLOCKS), b256, 0, stream>>>(qbuf, kbuf, out, partial);
    reduce_kernel<<<dim3(1), b256, 0, stream>>>(partial, out + REG_OFF);
}

// Round 8
// 257.961 us; speedup vs baseline: 1.1601x; 1.0427x over previous
//
#include <hip/hip_runtime.h>
#include <hip/hip_bf16.h>

#define D_MODEL 768
#define D_HIDDEN 2048
#define NHEADS 12
#define BATCH 4
#define SEQ 128
#define MROWS (BATCH*SEQ)                      // 512
#define SCORE_ELEMS (BATCH*NHEADS*SEQ*SEQ)     // 786432
#define REG_OFF SCORE_ELEMS
#define FIRES_OFF (SCORE_ELEMS + 1)
#define TRIGMAX 8192
#define NFIRES_BLOCKS 512

typedef __attribute__((ext_vector_type(8))) short bf16x8;
typedef __attribute__((ext_vector_type(4))) float f32x4;

static __device__ __forceinline__ unsigned short f2bf(float f) {
    union { float f; unsigned u; } v; v.f = f;
    unsigned u = v.u;
    return (unsigned short)((u + 0x7FFFu + ((u >> 16) & 1u)) >> 16);  // RNE
}

// ---------------------------------------------------------------------------
// Kernel 0: zero the trigger counter.
// ---------------------------------------------------------------------------
__global__ void init_kernel(unsigned* __restrict__ trigc) {
    if (threadIdx.x == 0) *trigc = 0u;
}

// ---------------------------------------------------------------------------
// Kernel 1: fused encoder GEMM  out = relu(x @ W + b) for Q (z=0) and K (z=1).
// M=512, N=2048, K=768. BM=64, BN=128, BK=16, fp32 accum. Grid (16,8,2)=256.
// ---------------------------------------------------------------------------
__global__ __launch_bounds__(256) void enc_kernel(
    const float* __restrict__ x,
    const float* __restrict__ WQ, const float* __restrict__ WK,
    const float* __restrict__ bQ, const float* __restrict__ bK,
    float* __restrict__ qbuf, float* __restrict__ kbuf,
    unsigned* __restrict__ trigc, unsigned* __restrict__ trig, int cap)
{
    __shared__ float xs[64][16];
    __shared__ float wt[16][128];
    const int bufid = blockIdx.z;
    const float* W    = bufid ? WK : WQ;
    const float* bias = bufid ? bK : bQ;
    float* outbuf     = bufid ? kbuf : qbuf;

    const int t  = threadIdx.x;
    const int m0 = blockIdx.y * 64;
    const int n0 = blockIdx.x * 128;
    const int rg = t >> 5;
    const int cg = t & 31;

    float acc[8][4];
    #pragma unroll
    for (int i = 0; i < 8; ++i)
        #pragma unroll
        for (int c = 0; c < 4; ++c) acc[i][c] = 0.f;

    for (int kk = 0; kk < D_MODEL; kk += 16) {
        #pragma unroll
        for (int u = 0; u < 4; ++u) {
            int idx = t + 256 * u; int r = idx >> 4, j = idx & 15;
            xs[r][j] = x[(size_t)(m0 + r) * D_MODEL + kk + j];
        }
        #pragma unroll
        for (int u = 0; u < 8; ++u) {
            int idx = t + 256 * u; int r = idx >> 7, c = idx & 127;
            wt[r][c] = W[(size_t)(kk + r) * D_HIDDEN + n0 + c];
        }
        __syncthreads();
        #pragma unroll
        for (int j = 0; j < 16; ++j) {
            float a[8];
            #pragma unroll
            for (int i = 0; i < 8; ++i) a[i] = xs[rg * 8 + i][j];
            const float4 wv = *reinterpret_cast<const float4*>(&wt[j][cg * 4]);
            const float wr[4] = {wv.x, wv.y, wv.z, wv.w};
            #pragma unroll
            for (int i = 0; i < 8; ++i)
                #pragma unroll
                for (int c = 0; c < 4; ++c) acc[i][c] = fmaf(a[i], wr[c], acc[i][c]);
        }
        __syncthreads();
    }

    #pragma unroll
    for (int i = 0; i < 8; ++i) {
        const int m = m0 + rg * 8 + i;
        const int hb = n0 + cg * 4;
        f32x4 ov;
        #pragma unroll
        for (int c = 0; c < 4; ++c) {
            const int h = hb + c;
            float pre = acc[i][c] + bias[h];
            if (fabsf(pre) < 3e-4f) {
                if (cap > 0) {
                    unsigned idx = atomicAdd(trigc, 1u);
                    if ((int)idx < cap)
                        trig[idx] = ((unsigned)bufid << 20) | ((unsigned)m << 11) | (unsigned)h;
                } else {
                    const float* xr = x + (size_t)m * D_MODEL;
                    const float* wc = W + h;
                    double s = (double)bias[h];
                    for (int dd = 0; dd < D_MODEL; ++dd)
                        s += (double)xr[dd] * (double)wc[(size_t)dd * D_HIDDEN];
                    pre = (float)s;
                }
            }
            ov[c] = fmaxf(pre, 0.f);
        }
        *reinterpret_cast<f32x4*>(outbuf + (size_t)m * D_HIDDEN + hb) = ov;
    }
}

// ---------------------------------------------------------------------------
// Kernel 1b: fp64 fix for near-zero preacts. One block per trigger (strided).
// ---------------------------------------------------------------------------
__global__ __launch_bounds__(256) void fix_kernel(
    const float* __restrict__ x,
    const float* __restrict__ WQ, const float* __restrict__ WK,
    const float* __restrict__ bQ, const float* __restrict__ bK,
    float* __restrict__ qbuf, float* __restrict__ kbuf,
    const unsigned* __restrict__ trigc, const unsigned* __restrict__ trig,
    int cap)
{
    __shared__ double red[4];
    const unsigned n = min(*trigc, (unsigned)cap);
    for (unsigned i = blockIdx.x; i < n; i += gridDim.x) {
        const unsigned e = trig[i];
        const int h = e & 2047, m = (e >> 11) & 511, bid = (int)(e >> 20);
        const float* W  = bid ? WK : WQ;
        const float* bb = bid ? bK : bQ;
        float* ob       = bid ? kbuf : qbuf;
        const float* xr = x + (size_t)m * D_MODEL;
        double s = 0.0;
        for (int dd = threadIdx.x; dd < D_MODEL; dd += 256)
            s += (double)xr[dd] * (double)W[(size_t)dd * D_HIDDEN + h];
        #pragma unroll
        for (int off = 32; off > 0; off >>= 1) s += __shfl_down(s, off);
        if ((threadIdx.x & 63) == 0) red[threadIdx.x >> 6] = s;
        __syncthreads();
        if (threadIdx.x == 0) {
            double tot = red[0] + red[1] + red[2] + red[3] + (double)bb[h];
            ob[(size_t)m * D_HIDDEN + h] = fmaxf((float)tot, 0.f);
        }
        __syncthreads();
    }
}

// ---------------------------------------------------------------------------
// Kernel 2: fires + reg partials -- PER-WAVE SEQUENTIAL STORE STREAM.
// Wave = (b, q, 32-k chunk) -> writes one contiguous ascending 256 KB window
// of out, 1KB per wave-store. Window shifted by -1 element so stores are 16B
// aligned (start FIRES_OFF-1, 64B aligned): row-sweep covers h=-1..2046 where
// h=-1 is the PREVIOUS row's h2047 (carry: qlast*k_{r-1}[2047]).
// K rows staged into LDS pre-shifted (8 rows/phase, 64KB) so LDS reads are
// aligned b128. Boundary cases: global-first element = reg slot (fake value,
// overwritten by reduce_kernel later, excluded from racc); k==0 rows use the
// (q-1) row product via direct loads; global-last element stored explicitly.
// grid = 4b * 32qc * 4kc = 512 blocks (2/CU), 4 waves/block (wave w -> q).
// ---------------------------------------------------------------------------
__global__ __launch_bounds__(256) void fires_kernel(
    const float* __restrict__ qbuf, const float* __restrict__ kbuf,
    float* __restrict__ out, float* __restrict__ partial)
{
    __shared__ float klds[8 * D_HIDDEN];       // 64 KB
    const int t  = threadIdx.x;
    const int w  = t >> 6;
    const int l  = t & 63;
    const int bi = blockIdx.x;
    const int kc = bi & 3;
    const int qc = (bi >> 2) & 31;
    const int b  = bi >> 7;

    const int qrow = b * SEQ + qc * 4 + w;
    const float* qr = qbuf + (size_t)qrow * D_HIDDEN;
    const size_t kbase = ((size_t)b * SEQ + kc * 32) * D_HIDDEN;

    // q registers: qs[j][e] = q[256j + 4l - 1 + e]  (scalar loads: 4B-safe)
    f32x4 qs[8];
    #pragma unroll
    for (int j = 0; j < 8; ++j) {
        const int off = 256 * j + 4 * l - 1;
        if (j == 0 && l == 0) {
            qs[0][0] = 0.f; qs[0][1] = qr[0]; qs[0][2] = qr[1]; qs[0][3] = qr[2];
        } else {
            qs[j][0] = qr[off + 0]; qs[j][1] = qr[off + 1];
            qs[j][2] = qr[off + 2]; qs[j][3] = qr[off + 3];
        }
    }
    const float qlast = qr[2047];

    // k==0 boundary: product for previous output row's h2047 (row (b,q-1,127))
    float x0sp = 0.f;
    bool havefake = false;
    if (kc == 0) {
        const int prevR = qrow * SEQ - 1;
        if (prevR >= 0) {
            const int pq = prevR >> 7;        // flat (b*128+q) of prev row
            const int pk = prevR & 127;
            const int pb = pq >> 7;
            x0sp = qbuf[(size_t)pq * D_HIDDEN + 2047]
                 * kbuf[((size_t)(pb * SEQ + pk)) * D_HIDDEN + 2047];
        } else {
            havefake = true;                   // window starts at the reg slot
        }
    }

    f32x4* out4 = reinterpret_cast<f32x4*>(out + FIRES_OFF - 1);  // 64B aligned
    const size_t R0 = (size_t)qrow * SEQ + (size_t)kc * 32;

    float racc = 0.f;
    for (int p = 0; p < 4; ++p) {
        __syncthreads();
        // stage 8 k-rows SHIFTED: klds[x] = kbuf[kbase + p*16384 + x - 1]
        {
            const float* src = kbuf + kbase + (size_t)p * 16384 - 1;
            #pragma unroll
            for (int u = 0; u < 16; ++u) {
                const int x4 = t + 256 * u;
                const float* s4 = src + (size_t)x4 * 4;
                f32x4 v; v[0] = s4[0]; v[1] = s4[1]; v[2] = s4[2]; v[3] = s4[3];
                *reinterpret_cast<f32x4*>(&klds[x4 * 4]) = v;
            }
        }
        __syncthreads();

        #pragma unroll 1
        for (int lr = 0; lr < 8; ++lr) {
            const int r = p * 8 + lr;
            f32x4 ks[8];
            #pragma unroll
            for (int j = 0; j < 8; ++j)
                ks[j] = *reinterpret_cast<const f32x4*>(&klds[lr * 2048 + 256 * j + 4 * l]);

            f32x4* orow = out4 + (R0 + r) * 512;
            float sacc = 0.f;
            #pragma unroll
            for (int j = 0; j < 8; ++j) {
                f32x4 pv;
                #pragma unroll
                for (int e = 0; e < 4; ++e) pv[e] = qs[j][e] * ks[j][e];
                if (j == 0 && l == 0)
                    pv[0] = (r == 0 && kc == 0) ? x0sp : qlast * ks[0][0];
                f32x4 f;
                #pragma unroll
                for (int e = 0; e < 4; ++e) f[e] = (pv[e] > 0.f) ? 1.f : 0.f;
                orow[j * 64 + l] = f;
                float s = (sqrtf(pv[0] + 1e-6f) + sqrtf(pv[1] + 1e-6f))
                        + (sqrtf(pv[2] + 1e-6f) + sqrtf(pv[3] + 1e-6f));
                if (j == 0 && l == 0 && r == 0 && havefake)
                    s -= sqrtf(pv[0] + 1e-6f);     // exclude the fake reg-slot elem
                sacc += s;
            }
            racc += sacc;
        }
    }

    // global-last element (b=3,q=127,k=127,h=2047): covered by nobody's window
    if (bi == NFIRES_BLOCKS - 1 && w == 3 && l == 0) {
        const float kv = kbuf[((size_t)(3 * SEQ + 127)) * D_HIDDEN + 2047];
        const float pv = qlast * kv;
        out[(size_t)(FIRES_OFF - 1) + (R0 + 32) * D_HIDDEN] = (pv > 0.f) ? 1.f : 0.f;
        racc += sqrtf(pv + 1e-6f);
    }

    #pragma unroll
    for (int off = 32; off > 0; off >>= 1) racc += __shfl_down(racc, off);
    __shared__ float rs[4];
    if (l == 0) rs[w] = racc;
    __syncthreads();
    if (t == 0) partial[bi] = (rs[0] + rs[1]) + (rs[2] + rs[3]);
}

// ---------------------------------------------------------------------------
// Kernel 2b: deterministic fixed-order reduction of block partials -> reg_loss.
// ---------------------------------------------------------------------------
__global__ __launch_bounds__(256) void reduce_kernel(
    const float* __restrict__ partial, float* __restrict__ reg)
{
    __shared__ float rs[4];
    const int t = threadIdx.x;
    float s = partial[t] + partial[t + 256];
    #pragma unroll
    for (int off = 32; off > 0; off >>= 1) s += __shfl_down(s, off);
    if ((t & 63) == 0) rs[t >> 6] = s;
    __syncthreads();
    if (t == 0) *reg = ((rs[0] + rs[1]) + (rs[2] + rs[3])) * 1e-3f;
}

// ---------------------------------------------------------------------------
// Kernel 3: score via bf16 MFMA, h-split across waves for occupancy.
// grid = 4b * 12n * 16 subtiles (32x32) = 768 blocks (3/CU).
// ---------------------------------------------------------------------------
__global__ __launch_bounds__(256) void score_kernel(
    const float* __restrict__ qbuf, const float* __restrict__ kbuf,
    const float* __restrict__ Wdec, const float* __restrict__ bdec,
    float* __restrict__ out)
{
    __shared__ float wcol[D_HIDDEN];
    __shared__ float red[4][64][16];
    const int t   = threadIdx.x;
    const int bi  = blockIdx.x;
    const int sub = bi & 15;
    const int pr  = bi >> 4;
    const int n   = pr % NHEADS;
    const int b   = pr / NHEADS;

    for (int idx = t; idx < D_HIDDEN; idx += 256)
        wcol[idx] = Wdec[(size_t)idx * NHEADS + n];
    __syncthreads();

    const int qt   = (sub >> 2) * 32;
    const int kt   = (sub & 3) * 32;
    const int w    = t >> 6;
    const int lane = t & 63;
    const int lrow = lane & 15;
    const int koff = (lane >> 4) * 8;

    f32x4 acc[2][2];
    #pragma unroll
    for (int i = 0; i < 2; ++i)
        #pragma unroll
        for (int j = 0; j < 2; ++j) { f32x4 z = {0.f, 0.f, 0.f, 0.f}; acc[i][j] = z; }

    const float* qb = qbuf + (size_t)b * SEQ * D_HIDDEN;
    const float* kb = kbuf + (size_t)b * SEQ * D_HIDDEN;

    const int hlo = w * 512;
    for (int kk = hlo; kk < hlo + 512; kk += 32) {
        const int h0 = kk + koff;
        float wv[8];
        #pragma unroll
        for (int i = 0; i < 8; ++i) wv[i] = wcol[h0 + i];

        bf16x8 afrag[2], bfrag[2];
        #pragma unroll
        for (int fi = 0; fi < 2; ++fi) {
            const float* qp = qb + (size_t)(qt + fi * 16 + lrow) * D_HIDDEN + h0;
            const float4 q1 = *reinterpret_cast<const float4*>(qp);
            const float4 q2 = *reinterpret_cast<const float4*>(qp + 4);
            const float qf[8] = {q1.x, q1.y, q1.z, q1.w, q2.x, q2.y, q2.z, q2.w};
            #pragma unroll
            for (int i = 0; i < 8; ++i) afrag[fi][i] = (short)f2bf(qf[i] * wv[i]);
        }
        #pragma unroll
        for (int fj = 0; fj < 2; ++fj) {
            const float* kp = kb + (size_t)(kt + fj * 16 + lrow) * D_HIDDEN + h0;
            const float4 k1 = *reinterpret_cast<const float4*>(kp);
            const float4 k2 = *reinterpret_cast<const float4*>(kp + 4);
            const float kf[8] = {k1.x, k1.y, k1.z, k1.w, k2.x, k2.y, k2.z, k2.w};
            #pragma unroll
            for (int i = 0; i < 8; ++i) bfrag[fj][i] = (short)f2bf(kf[i]);
        }
        #pragma unroll
        for (int fi = 0; fi < 2; ++fi)
            #pragma unroll
            for (int fj = 0; fj < 2; ++fj)
                acc[fi][fj] = __builtin_amdgcn_mfma_f32_16x16x32_bf16(
                    afrag[fi], bfrag[fj], acc[fi][fj], 0, 0, 0);
    }

    #pragma unroll
    for (int fi = 0; fi < 2; ++fi)
        #pragma unroll
        for (int fj = 0; fj < 2; ++fj)
            #pragma unroll
            for (int j = 0; j < 4; ++j)
                red[w][lane][fi * 8 + fj * 4 + j] = acc[fi][fj][j];
    __syncthreads();

    const float bd   = bdec[n];
    const int   outb = (b * NHEADS + n) * SEQ * SEQ;
    #pragma unroll
    for (int u = 0; u < 4; ++u) {
        const int j = w * 4 + u;
        const float s = (red[0][lane][j] + red[1][lane][j])
                      + (red[2][lane][j] + red[3][lane][j]);
        const int fi = j >> 3, fj = (j >> 2) & 1, jj = j & 3;
        const int row = qt + fi * 16 + (lane >> 4) * 4 + jj;
        const int col = kt + fj * 16 + (lane & 15);
        out[outb + row * SEQ + col] = s * 0.125f + bd;
    }
}

// ---------------------------------------------------------------------------
extern "C" void kernel_launch(void* const* d_in, const int* in_sizes, int n_in,
                              void* d_out, int out_size, void* d_ws, size_t ws_size,
                              hipStream_t stream) {
    const float* x  = (const float*)d_in[0];
    const float* WQ = (const float*)d_in[1];
    const float* WK = (const float*)d_in[2];
    const float* bQ = (const float*)d_in[3];
    const float* bK = (const float*)d_in[4];
    const float* Wd = (const float*)d_in[5];
    const float* bd = (const float*)d_in[6];
    float* out  = (float*)d_out;
    float* qbuf = (float*)d_ws;                                // 4 MB
    float* kbuf = qbuf + (size_t)MROWS * D_HIDDEN;             // 4 MB
    float* partial = kbuf + (size_t)MROWS * D_HIDDEN;          // 512 floats
    unsigned* trigc = (unsigned*)(partial + NFIRES_BLOCKS);
    unsigned* trig  = trigc + 1;
    const size_t need = (size_t)8 * 1024 * 1024 + NFIRES_BLOCKS * 4 + 4 + (size_t)TRIGMAX * 4;
    const int cap = (ws_size >= need) ? TRIGMAX : 0;

    dim3 b256(256);

    if (cap > 0) init_kernel<<<dim3(1), dim3(64), 0, stream>>>(trigc);

    enc_kernel<<<dim3(D_HIDDEN / 128, MROWS / 64, 2), b256, 0, stream>>>(
        x, WQ, WK, bQ, bK, qbuf, kbuf, trigc, trig, cap);
    if (cap > 0)
        fix_kernel<<<dim3(128), b256, 0, stream>>>(x, WQ, WK, bQ, bK, qbuf, kbuf, trigc, trig, cap);

    score_kernel<<<dim3(BATCH * NHEADS * 16), b256, 0, stream>>>(qbuf, kbuf, Wd, bd, out);
    fires_kernel<<<dim3(NFIRES_BLOCKS), b256, 0, stream>>>(qbuf, kbuf, out, partial);
    reduce_kernel<<<dim3(1), b256, 0, stream>>>(partial, out + REG_OFF);
}

// Round 9
// 216.955 us; speedup vs baseline: 1.3794x; 1.1890x over previous
//
#include <hip/hip_runtime.h>
#include <hip/hip_bf16.h>

#define D_MODEL 768
#define D_HIDDEN 2048
#define NHEADS 12
#define BATCH 4
#define SEQ 128
#define MROWS (BATCH*SEQ)                      // 512
#define SCORE_ELEMS (BATCH*NHEADS*SEQ*SEQ)     // 786432
#define REG_OFF SCORE_ELEMS
#define FIRES_OFF (SCORE_ELEMS + 1)
#define TRIGMAX 8192
#define NROWS_T 65536                          // fires rows (b,q,k)
#define FIRES_WAVES 2048
#define FIRES_BLOCKS 512
#define SCORE_BLOCKS (BATCH*NHEADS*16)         // 768

typedef __attribute__((ext_vector_type(8))) short bf16x8;
typedef __attribute__((ext_vector_type(4))) float f32x4;

static __device__ __forceinline__ unsigned short f2bf(float f) {
    union { float f; unsigned u; } v; v.f = f;
    unsigned u = v.u;
    return (unsigned short)((u + 0x7FFFu + ((u >> 16) & 1u)) >> 16);  // RNE
}

// split v (fp32) into bf16 hi + bf16 lo with v ~ hi + lo to ~2^-18 relative.
static __device__ __forceinline__ void split_bf16(float v, short& hi, short& lo) {
    unsigned short h = f2bf(v);
    float hf = __uint_as_float((unsigned)h << 16);
    float lf = v - hf;                    // exact (Sterbenz)
    hi = (short)h;
    lo = (short)f2bf(lf);
}

// ---------------------------------------------------------------------------
// Kernel 0: zero the trigger counter.
// ---------------------------------------------------------------------------
__global__ void init_kernel(unsigned* __restrict__ trigc) {
    if (threadIdx.x == 0) *trigc = 0u;
}

// ---------------------------------------------------------------------------
// Kernel 1: encoder GEMM via SPLIT-BF16 MFMA.  out = relu(x @ W + b).
// x = xh + xl, W = wh + wl (bf16 splits, built inline from fp32 loads);
// acc += xh*wh + xh*wl + xl*wh  (fp32 MFMA accum; missing xl*wl <= ~2e-5,
// far inside the 3e-4 fp64-fix band, so fires signs stay exact).
// Wave = 32x32 output tile, block = 64x64. Grid (32, 8, 2) = 512 blocks.
// ---------------------------------------------------------------------------
__global__ __launch_bounds__(256) void enc_kernel(
    const float* __restrict__ x,
    const float* __restrict__ WQ, const float* __restrict__ WK,
    const float* __restrict__ bQ, const float* __restrict__ bK,
    float* __restrict__ qbuf, float* __restrict__ kbuf,
    unsigned* __restrict__ trigc, unsigned* __restrict__ trig, int cap)
{
    const int bufid = blockIdx.z;
    const float* W    = bufid ? WK : WQ;
    const float* bias = bufid ? bK : bQ;
    float* outbuf     = bufid ? kbuf : qbuf;

    const int t  = threadIdx.x;
    const int w  = t >> 6;
    const int l  = t & 63;
    const int mt = blockIdx.y * 64 + (w >> 1) * 32;
    const int nt = blockIdx.x * 64 + (w & 1) * 32;
    const int lr = l & 15;
    const int hg = (l >> 4) * 8;

    f32x4 acc[2][2];
    #pragma unroll
    for (int i = 0; i < 2; ++i)
        #pragma unroll
        for (int j = 0; j < 2; ++j) { f32x4 z = {0.f, 0.f, 0.f, 0.f}; acc[i][j] = z; }

    for (int kk = 0; kk < D_MODEL; kk += 32) {
        const int h0 = kk + hg;
        bf16x8 ah[2], al[2], bh[2], bl[2];
        #pragma unroll
        for (int fi = 0; fi < 2; ++fi) {
            const float* xp = x + (size_t)(mt + fi * 16 + lr) * D_MODEL + h0;
            const float4 v1 = *reinterpret_cast<const float4*>(xp);
            const float4 v2 = *reinterpret_cast<const float4*>(xp + 4);
            const float vv[8] = {v1.x, v1.y, v1.z, v1.w, v2.x, v2.y, v2.z, v2.w};
            #pragma unroll
            for (int i = 0; i < 8; ++i) {
                short h_, lo_;
                split_bf16(vv[i], h_, lo_);
                ah[fi][i] = h_; al[fi][i] = lo_;
            }
        }
        #pragma unroll
        for (int fj = 0; fj < 2; ++fj) {
            const int col = nt + fj * 16 + lr;
            #pragma unroll
            for (int i = 0; i < 8; ++i) {
                short h_, lo_;
                split_bf16(W[(size_t)(h0 + i) * D_HIDDEN + col], h_, lo_);
                bh[fj][i] = h_; bl[fj][i] = lo_;
            }
        }
        #pragma unroll
        for (int fi = 0; fi < 2; ++fi)
            #pragma unroll
            for (int fj = 0; fj < 2; ++fj) {
                acc[fi][fj] = __builtin_amdgcn_mfma_f32_16x16x32_bf16(
                    ah[fi], bh[fj], acc[fi][fj], 0, 0, 0);
                acc[fi][fj] = __builtin_amdgcn_mfma_f32_16x16x32_bf16(
                    ah[fi], bl[fj], acc[fi][fj], 0, 0, 0);
                acc[fi][fj] = __builtin_amdgcn_mfma_f32_16x16x32_bf16(
                    al[fi], bh[fj], acc[fi][fj], 0, 0, 0);
            }
    }

    #pragma unroll
    for (int fi = 0; fi < 2; ++fi)
        #pragma unroll
        for (int fj = 0; fj < 2; ++fj)
            #pragma unroll
            for (int j = 0; j < 4; ++j) {
                const int row = mt + fi * 16 + (l >> 4) * 4 + j;
                const int col = nt + fj * 16 + lr;
                float pre = acc[fi][fj][j] + bias[col];
                if (fabsf(pre) < 3e-4f) {
                    if (cap > 0) {
                        unsigned idx = atomicAdd(trigc, 1u);
                        if ((int)idx < cap)
                            trig[idx] = ((unsigned)bufid << 20) | ((unsigned)row << 11) | (unsigned)col;
                    } else {
                        const float* xr = x + (size_t)row * D_MODEL;
                        const float* wc = W + col;
                        double s = (double)bias[col];
                        for (int dd = 0; dd < D_MODEL; ++dd)
                            s += (double)xr[dd] * (double)wc[(size_t)dd * D_HIDDEN];
                        pre = (float)s;
                    }
                }
                outbuf[(size_t)row * D_HIDDEN + col] = fmaxf(pre, 0.f);
            }
}

// ---------------------------------------------------------------------------
// Kernel 1b: fp64 fix for near-zero preacts. One block per trigger (strided).
// ---------------------------------------------------------------------------
__global__ __launch_bounds__(256) void fix_kernel(
    const float* __restrict__ x,
    const float* __restrict__ WQ, const float* __restrict__ WK,
    const float* __restrict__ bQ, const float* __restrict__ bK,
    float* __restrict__ qbuf, float* __restrict__ kbuf,
    const unsigned* __restrict__ trigc, const unsigned* __restrict__ trig,
    int cap)
{
    __shared__ double red[4];
    const unsigned n = min(*trigc, (unsigned)cap);
    for (unsigned i = blockIdx.x; i < n; i += gridDim.x) {
        const unsigned e = trig[i];
        const int h = e & 2047, m = (e >> 11) & 511, bid = (int)(e >> 20);
        const float* W  = bid ? WK : WQ;
        const float* bb = bid ? bK : bQ;
        float* ob       = bid ? kbuf : qbuf;
        const float* xr = x + (size_t)m * D_MODEL;
        double s = 0.0;
        for (int dd = threadIdx.x; dd < D_MODEL; dd += 256)
            s += (double)xr[dd] * (double)W[(size_t)dd * D_HIDDEN + h];
        #pragma unroll
        for (int off = 32; off > 0; off >>= 1) s += __shfl_down(s, off);
        if ((threadIdx.x & 63) == 0) red[threadIdx.x >> 6] = s;
        __syncthreads();
        if (threadIdx.x == 0) {
            double tot = red[0] + red[1] + red[2] + red[3] + (double)bb[h];
            ob[(size_t)m * D_HIDDEN + h] = fmaxf((float)tot, 0.f);
        }
        __syncthreads();
    }
}

// ---------------------------------------------------------------------------
// Kernel 2: COMBINED score (blocks < 768) + fires (blocks 768..1279).
//
// Fires: DENSE MOVING FRONT. Wave g handles rows R = g + s*2048, so at step s
// ALL chip stores land in one contiguous 16 MB window that sweeps the output
// front-to-back (the fill kernel's pattern: HBM row-buffer locality), instead
// of 2048 scattered per-wave windows. No LDS; -1-shifted 16B-aligned stores;
// in-wave __shfl supplies the h=4l-1 neighbor; (R-1,2047) boundary via 2
// scalar loads; fake first slot excluded from racc; global-last in epilogue.
//
// Score (unchanged, verified): per (b,n,32x32 tile), h-split across 4 waves.
// ---------------------------------------------------------------------------
__global__ __launch_bounds__(256) void main_kernel(
    const float* __restrict__ qbuf, const float* __restrict__ kbuf,
    const float* __restrict__ Wdec, const float* __restrict__ bdec,
    float* __restrict__ out, float* __restrict__ partial)
{
    __shared__ float wcol[D_HIDDEN];
    __shared__ float red[4][64][16];
    __shared__ float rs[4];
    const int t  = threadIdx.x;
    const int bi = blockIdx.x;

    if (bi < SCORE_BLOCKS) {
        // ----------------------------- score -----------------------------
        const int sub = bi & 15;
        const int pr  = bi >> 4;
        const int n   = pr % NHEADS;
        const int b   = pr / NHEADS;

        for (int idx = t; idx < D_HIDDEN; idx += 256)
            wcol[idx] = Wdec[(size_t)idx * NHEADS + n];
        __syncthreads();

        const int qt   = (sub >> 2) * 32;
        const int kt   = (sub & 3) * 32;
        const int w    = t >> 6;
        const int lane = t & 63;
        const int lrow = lane & 15;
        const int koff = (lane >> 4) * 8;

        f32x4 acc[2][2];
        #pragma unroll
        for (int i = 0; i < 2; ++i)
            #pragma unroll
            for (int j = 0; j < 2; ++j) { f32x4 z = {0.f, 0.f, 0.f, 0.f}; acc[i][j] = z; }

        const float* qb = qbuf + (size_t)b * SEQ * D_HIDDEN;
        const float* kb = kbuf + (size_t)b * SEQ * D_HIDDEN;

        const int hlo = w * 512;
        for (int kk = hlo; kk < hlo + 512; kk += 32) {
            const int h0 = kk + koff;
            float wv[8];
            #pragma unroll
            for (int i = 0; i < 8; ++i) wv[i] = wcol[h0 + i];

            bf16x8 afrag[2], bfrag[2];
            #pragma unroll
            for (int fi = 0; fi < 2; ++fi) {
                const float* qp = qb + (size_t)(qt + fi * 16 + lrow) * D_HIDDEN + h0;
                const float4 q1 = *reinterpret_cast<const float4*>(qp);
                const float4 q2 = *reinterpret_cast<const float4*>(qp + 4);
                const float qf[8] = {q1.x, q1.y, q1.z, q1.w, q2.x, q2.y, q2.z, q2.w};
                #pragma unroll
                for (int i = 0; i < 8; ++i) afrag[fi][i] = (short)f2bf(qf[i] * wv[i]);
            }
            #pragma unroll
            for (int fj = 0; fj < 2; ++fj) {
                const float* kp = kb + (size_t)(kt + fj * 16 + lrow) * D_HIDDEN + h0;
                const float4 k1 = *reinterpret_cast<const float4*>(kp);
                const float4 k2 = *reinterpret_cast<const float4*>(kp + 4);
                const float kf[8] = {k1.x, k1.y, k1.z, k1.w, k2.x, k2.y, k2.z, k2.w};
                #pragma unroll
                for (int i = 0; i < 8; ++i) bfrag[fj][i] = (short)f2bf(kf[i]);
            }
            #pragma unroll
            for (int fi = 0; fi < 2; ++fi)
                #pragma unroll
                for (int fj = 0; fj < 2; ++fj)
                    acc[fi][fj] = __builtin_amdgcn_mfma_f32_16x16x32_bf16(
                        afrag[fi], bfrag[fj], acc[fi][fj], 0, 0, 0);
        }

        #pragma unroll
        for (int fi = 0; fi < 2; ++fi)
            #pragma unroll
            for (int fj = 0; fj < 2; ++fj)
                #pragma unroll
                for (int j = 0; j < 4; ++j)
                    red[w][lane][fi * 8 + fj * 4 + j] = acc[fi][fj][j];
        __syncthreads();

        const float bd   = bdec[n];
        const int   outb = (b * NHEADS + n) * SEQ * SEQ;
        #pragma unroll
        for (int u = 0; u < 4; ++u) {
            const int j = w * 4 + u;
            const float s = (red[0][lane][j] + red[1][lane][j])
                          + (red[2][lane][j] + red[3][lane][j]);
            const int fi = j >> 3, fj = (j >> 2) & 1, jj = j & 3;
            const int row = qt + fi * 16 + (lane >> 4) * 4 + jj;
            const int col = kt + fj * 16 + (lane & 15);
            out[outb + row * SEQ + col] = s * 0.125f + bd;
        }
        return;
    }

    // ------------------------------- fires -------------------------------
    const int w = t >> 6;
    const int l = t & 63;
    const int g = (bi - SCORE_BLOCKS) * 4 + w;           // 0..2047

    f32x4* out4 = reinterpret_cast<f32x4*>(out + FIRES_OFF - 1);  // 16B aligned
    float racc = 0.f;

    #pragma unroll 1
    for (int s = 0; s < NROWS_T / FIRES_WAVES; ++s) {
        const int R    = g + s * FIRES_WAVES;
        const int brow = R >> 7;                          // global q-row
        const int b    = brow >> 7;
        const int krow = (b << 7) + (R & 127);
        const float* qr = qbuf + (size_t)brow * D_HIDDEN;
        const float* kr = kbuf + (size_t)krow * D_HIDDEN;

        f32x4 qv[8], kv[8];
        #pragma unroll
        for (int j = 0; j < 8; ++j) {
            qv[j] = *reinterpret_cast<const f32x4*>(qr + 256 * j + 4 * l);
            kv[j] = *reinterpret_cast<const f32x4*>(kr + 256 * j + 4 * l);
        }

        // boundary product for this row's h=-1 slot = element (R-1, 2047)
        float pm1 = 0.f;
        if (l == 0 && R > 0) {
            const int pbrow = (R - 1) >> 7;
            const int pb    = pbrow >> 7;
            const int pkrow = (pb << 7) + ((R - 1) & 127);
            pm1 = qbuf[(size_t)pbrow * D_HIDDEN + 2047]
                * kbuf[(size_t)pkrow * D_HIDDEN + 2047];
        }

        // neighbor values for h = 4l-1: lane l-1's elem3 (lane0: lane63 of j-1)
        float q3[8], k3[8], q63[8], k63[8];
        #pragma unroll
        for (int j = 0; j < 8; ++j) {
            q3[j]  = __shfl_up(qv[j][3], 1);
            k3[j]  = __shfl_up(kv[j][3], 1);
            q63[j] = __shfl(qv[j][3], 63);
            k63[j] = __shfl(kv[j][3], 63);
        }

        #pragma unroll
        for (int j = 0; j < 8; ++j) {
            float p0;
            if (l == 0) {
                p0 = (j == 0) ? pm1 : q63[j - 1] * k63[j - 1];
            } else {
                p0 = q3[j] * k3[j];
            }
            const float p1 = qv[j][0] * kv[j][0];
            const float p2 = qv[j][1] * kv[j][1];
            const float p3 = qv[j][2] * kv[j][2];
            f32x4 f;
            f[0] = (p0 > 0.f) ? 1.f : 0.f;
            f[1] = (p1 > 0.f) ? 1.f : 0.f;
            f[2] = (p2 > 0.f) ? 1.f : 0.f;
            f[3] = (p3 > 0.f) ? 1.f : 0.f;
            out4[(size_t)R * 512 + 64 * j + l] = f;
            racc += (sqrtf(p0 + 1e-6f) + sqrtf(p1 + 1e-6f))
                  + (sqrtf(p2 + 1e-6f) + sqrtf(p3 + 1e-6f));
        }
    }

    // exclude the fake first slot's sqrt (R=0, j=0, l=0, p0 = 0)
    if (g == 0 && l == 0) racc -= sqrtf(0.f + 1e-6f);
    // global-last element (row 65535, h=2047)
    if (g == FIRES_WAVES - 1 && l == 0) {
        const float pv = qbuf[(size_t)511 * D_HIDDEN + 2047]
                       * kbuf[(size_t)511 * D_HIDDEN + 2047];
        out[(size_t)(FIRES_OFF - 1) + (size_t)NROWS_T * D_HIDDEN] = (pv > 0.f) ? 1.f : 0.f;
        racc += sqrtf(pv + 1e-6f);
    }

    #pragma unroll
    for (int off = 32; off > 0; off >>= 1) racc += __shfl_down(racc, off);
    if (l == 0) rs[w] = racc;
    __syncthreads();
    if (t == 0) partial[bi - SCORE_BLOCKS] = (rs[0] + rs[1]) + (rs[2] + rs[3]);
}

// ---------------------------------------------------------------------------
// Kernel 2b: deterministic fixed-order reduction of block partials -> reg_loss.
// ---------------------------------------------------------------------------
__global__ __launch_bounds__(256) void reduce_kernel(
    const float* __restrict__ partial, float* __restrict__ reg)
{
    __shared__ float rs[4];
    const int t = threadIdx.x;
    float s = partial[t] + partial[t + 256];
    #pragma unroll
    for (int off = 32; off > 0; off >>= 1) s += __shfl_down(s, off);
    if ((t & 63) == 0) rs[t >> 6] = s;
    __syncthreads();
    if (t == 0) *reg = ((rs[0] + rs[1]) + (rs[2] + rs[3])) * 1e-3f;
}

// ---------------------------------------------------------------------------
extern "C" void kernel_launch(void* const* d_in, const int* in_sizes, int n_in,
                              void* d_out, int out_size, void* d_ws, size_t ws_size,
                              hipStream_t stream) {
    const float* x  = (const float*)d_in[0];
    const float* WQ = (const float*)d_in[1];
    const float* WK = (const float*)d_in[2];
    const float* bQ = (const float*)d_in[3];
    const float* bK = (const float*)d_in[4];
    const float* Wd = (const float*)d_in[5];
    const float* bd = (const float*)d_in[6];
    float* out  = (float*)d_out;
    float* qbuf = (float*)d_ws;                                // 4 MB
    float* kbuf = qbuf + (size_t)MROWS * D_HIDDEN;             // 4 MB
    float* partial = kbuf + (size_t)MROWS * D_HIDDEN;          // 512 floats
    unsigned* trigc = (unsigned*)(partial + FIRES_BLOCKS);
    unsigned* trig  = trigc + 1;
    const size_t need = (size_t)8 * 1024 * 1024 + FIRES_BLOCKS * 4 + 4 + (size_t)TRIGMAX * 4;
    const int cap = (ws_size >= need) ? TRIGMAX : 0;

    dim3 b256(256);

    if (cap > 0) init_kernel<<<dim3(1), dim3(64), 0, stream>>>(trigc);

    enc_kernel<<<dim3(D_HIDDEN / 64, MROWS / 64, 2), b256, 0, stream>>>(
        x, WQ, WK, bQ, bK, qbuf, kbuf, trigc, trig, cap);
    if (cap > 0)
        fix_kernel<<<dim3(128), b256, 0, stream>>>(x, WQ, WK, bQ, bK, qbuf, kbuf, trigc, trig, cap);

    main_kernel<<<dim3(SCORE_BLOCKS + FIRES_BLOCKS), b256, 0, stream>>>(
        qbuf, kbuf, Wd, bd, out, partial);
    reduce_kernel<<<dim3(1), b256, 0, stream>>>(partial, out + REG_OFF);
}

// Round 10
// 175.379 us; speedup vs baseline: 1.7064x; 1.2371x over previous
//
#include <hip/hip_runtime.h>
#include <hip/hip_bf16.h>

#define D_MODEL 768
#define D_HIDDEN 2048
#define NHEADS 12
#define BATCH 4
#define SEQ 128
#define MROWS (BATCH*SEQ)                      // 512
#define SCORE_ELEMS (BATCH*NHEADS*SEQ*SEQ)     // 786432
#define REG_OFF SCORE_ELEMS
#define FIRES_OFF (SCORE_ELEMS + 1)
#define NROWS_T 65536                          // fires rows (b,q,k)
#define FIRES_WAVES 2048
#define FIRES_BLOCKS 512
#define SCORE_BLOCKS (BATCH*NHEADS*16)         // 768
#define TRIGCAP 64

typedef __attribute__((ext_vector_type(8))) short bf16x8;
typedef __attribute__((ext_vector_type(4))) float f32x4;

static __device__ __forceinline__ unsigned short f2bf(float f) {
    union { float f; unsigned u; } v; v.f = f;
    unsigned u = v.u;
    return (unsigned short)((u + 0x7FFFu + ((u >> 16) & 1u)) >> 16);  // RNE
}

// split v (fp32) into bf16 hi + bf16 lo with v ~ hi + lo to ~2^-18 relative.
static __device__ __forceinline__ void split_bf16(float v, short& hi, short& lo) {
    unsigned short h = f2bf(v);
    float hf = __uint_as_float((unsigned)h << 16);
    float lf = v - hf;
    hi = (short)h;
    lo = (short)f2bf(lf);
}

// ---------------------------------------------------------------------------
// Kernel 1: encoder GEMM via SPLIT-BF16 MFMA + INLINE block-local fp64 fix.
// out = relu(x @ W + b); acc += xh*wh + xh*wl + xl*wh (missing xl*wl ~2e-5).
// Near-zero preacts (|pre|<3e-4) go to an LDS list; at block end all 256
// threads cooperatively recompute each in fp64 (3 terms/thread + reduce).
// Block (0,0,0) zeroes out[REG_OFF]. Grid (32, 8, 2) = 512 blocks.
// ---------------------------------------------------------------------------
__global__ __launch_bounds__(256) void enc_kernel(
    const float* __restrict__ x,
    const float* __restrict__ WQ, const float* __restrict__ WK,
    const float* __restrict__ bQ, const float* __restrict__ bK,
    float* __restrict__ qbuf, float* __restrict__ kbuf,
    float* __restrict__ out)
{
    __shared__ unsigned tcnt;
    __shared__ unsigned tlist[TRIGCAP];
    __shared__ double   redd[4];

    const int bufid = blockIdx.z;
    const float* W    = bufid ? WK : WQ;
    const float* bias = bufid ? bK : bQ;
    float* outbuf     = bufid ? kbuf : qbuf;

    const int t  = threadIdx.x;
    if (t == 0) tcnt = 0u;
    if (blockIdx.x == 0 && blockIdx.y == 0 && blockIdx.z == 0 && t == 0)
        out[REG_OFF] = 0.f;
    __syncthreads();

    const int w  = t >> 6;
    const int l  = t & 63;
    const int mt = blockIdx.y * 64 + (w >> 1) * 32;
    const int nt = blockIdx.x * 64 + (w & 1) * 32;
    const int lr = l & 15;
    const int hg = (l >> 4) * 8;

    f32x4 acc[2][2];
    #pragma unroll
    for (int i = 0; i < 2; ++i)
        #pragma unroll
        for (int j = 0; j < 2; ++j) { f32x4 z = {0.f, 0.f, 0.f, 0.f}; acc[i][j] = z; }

    for (int kk = 0; kk < D_MODEL; kk += 32) {
        const int h0 = kk + hg;
        bf16x8 ah[2], al[2], bh[2], bl[2];
        #pragma unroll
        for (int fi = 0; fi < 2; ++fi) {
            const float* xp = x + (size_t)(mt + fi * 16 + lr) * D_MODEL + h0;
            const float4 v1 = *reinterpret_cast<const float4*>(xp);
            const float4 v2 = *reinterpret_cast<const float4*>(xp + 4);
            const float vv[8] = {v1.x, v1.y, v1.z, v1.w, v2.x, v2.y, v2.z, v2.w};
            #pragma unroll
            for (int i = 0; i < 8; ++i) {
                short h_, lo_;
                split_bf16(vv[i], h_, lo_);
                ah[fi][i] = h_; al[fi][i] = lo_;
            }
        }
        #pragma unroll
        for (int fj = 0; fj < 2; ++fj) {
            const int col = nt + fj * 16 + lr;
            #pragma unroll
            for (int i = 0; i < 8; ++i) {
                short h_, lo_;
                split_bf16(W[(size_t)(h0 + i) * D_HIDDEN + col], h_, lo_);
                bh[fj][i] = h_; bl[fj][i] = lo_;
            }
        }
        #pragma unroll
        for (int fi = 0; fi < 2; ++fi)
            #pragma unroll
            for (int fj = 0; fj < 2; ++fj) {
                acc[fi][fj] = __builtin_amdgcn_mfma_f32_16x16x32_bf16(
                    ah[fi], bh[fj], acc[fi][fj], 0, 0, 0);
                acc[fi][fj] = __builtin_amdgcn_mfma_f32_16x16x32_bf16(
                    ah[fi], bl[fj], acc[fi][fj], 0, 0, 0);
                acc[fi][fj] = __builtin_amdgcn_mfma_f32_16x16x32_bf16(
                    al[fi], bh[fj], acc[fi][fj], 0, 0, 0);
            }
    }

    #pragma unroll
    for (int fi = 0; fi < 2; ++fi)
        #pragma unroll
        for (int fj = 0; fj < 2; ++fj)
            #pragma unroll
            for (int j = 0; j < 4; ++j) {
                const int row = mt + fi * 16 + (l >> 4) * 4 + j;
                const int col = nt + fj * 16 + lr;
                float pre = acc[fi][fj][j] + bias[col];
                if (fabsf(pre) < 3e-4f) {
                    unsigned idx = atomicAdd(&tcnt, 1u);
                    if (idx < TRIGCAP) {
                        tlist[idx] = ((unsigned)row << 11) | (unsigned)col;
                    } else {
                        // overflow fallback: serial fp64 (effectively never)
                        const float* xr = x + (size_t)row * D_MODEL;
                        const float* wc = W + col;
                        double s = (double)bias[col];
                        for (int dd = 0; dd < D_MODEL; ++dd)
                            s += (double)xr[dd] * (double)wc[(size_t)dd * D_HIDDEN];
                        pre = (float)s;
                    }
                }
                outbuf[(size_t)row * D_HIDDEN + col] = fmaxf(pre, 0.f);
            }

    __syncthreads();
    const unsigned n = min(tcnt, (unsigned)TRIGCAP);
    for (unsigned i = 0; i < n; ++i) {
        const unsigned e = tlist[i];
        const int hh = (int)(e & 2047u);
        const int mm = (int)(e >> 11);
        double s = 0.0;
        #pragma unroll
        for (int k = 0; k < 3; ++k) {
            const int dd = t + k * 256;
            s += (double)x[(size_t)mm * D_MODEL + dd]
               * (double)W[(size_t)dd * D_HIDDEN + hh];
        }
        #pragma unroll
        for (int off = 32; off > 0; off >>= 1) s += __shfl_down(s, off);
        if (l == 0) redd[w] = s;
        __syncthreads();
        if (t == 0) {
            double tot = redd[0] + redd[1] + redd[2] + redd[3] + (double)bias[hh];
            outbuf[(size_t)mm * D_HIDDEN + hh] = fmaxf((float)tot, 0.f);
        }
        __syncthreads();
    }
}

// ---------------------------------------------------------------------------
// Kernel 2: COMBINED score (blocks < 768) + fires (blocks 768..1279).
//
// Fires: dense moving front + NONTEMPORAL stores (write stream bypasses
// L2/L3 allocation so it stops thrashing the q/k working set) + k-row
// register caching (krow = (s>>3)*128 + (g&127): constant for 8 steps ->
// outer b-loop loads k once; only the q-row reloads per step; read traffic
// ~0.55 GB instead of ~1 GB). -1-shifted 16B-aligned stores; shfl neighbor
// machinery; R==0 corner store split to scalars so out[REG_OFF] is never
// touched by the vector store. reg partial -> one atomicAdd per block.
// ---------------------------------------------------------------------------
__global__ __launch_bounds__(256) void main_kernel(
    const float* __restrict__ qbuf, const float* __restrict__ kbuf,
    const float* __restrict__ Wdec, const float* __restrict__ bdec,
    float* __restrict__ out)
{
    __shared__ float wcol[D_HIDDEN];
    __shared__ float red[4][64][16];
    __shared__ float rs[4];
    const int t  = threadIdx.x;
    const int bi = blockIdx.x;

    if (bi < SCORE_BLOCKS) {
        // ----------------------------- score -----------------------------
        const int sub = bi & 15;
        const int pr  = bi >> 4;
        const int n   = pr % NHEADS;
        const int b   = pr / NHEADS;

        for (int idx = t; idx < D_HIDDEN; idx += 256)
            wcol[idx] = Wdec[(size_t)idx * NHEADS + n];
        __syncthreads();

        const int qt   = (sub >> 2) * 32;
        const int kt   = (sub & 3) * 32;
        const int w    = t >> 6;
        const int lane = t & 63;
        const int lrow = lane & 15;
        const int koff = (lane >> 4) * 8;

        f32x4 acc[2][2];
        #pragma unroll
        for (int i = 0; i < 2; ++i)
            #pragma unroll
            for (int j = 0; j < 2; ++j) { f32x4 z = {0.f, 0.f, 0.f, 0.f}; acc[i][j] = z; }

        const float* qb = qbuf + (size_t)b * SEQ * D_HIDDEN;
        const float* kb = kbuf + (size_t)b * SEQ * D_HIDDEN;

        const int hlo = w * 512;
        for (int kk = hlo; kk < hlo + 512; kk += 32) {
            const int h0 = kk + koff;
            float wv[8];
            #pragma unroll
            for (int i = 0; i < 8; ++i) wv[i] = wcol[h0 + i];

            bf16x8 afrag[2], bfrag[2];
            #pragma unroll
            for (int fi = 0; fi < 2; ++fi) {
                const float* qp = qb + (size_t)(qt + fi * 16 + lrow) * D_HIDDEN + h0;
                const float4 q1 = *reinterpret_cast<const float4*>(qp);
                const float4 q2 = *reinterpret_cast<const float4*>(qp + 4);
                const float qf[8] = {q1.x, q1.y, q1.z, q1.w, q2.x, q2.y, q2.z, q2.w};
                #pragma unroll
                for (int i = 0; i < 8; ++i) afrag[fi][i] = (short)f2bf(qf[i] * wv[i]);
            }
            #pragma unroll
            for (int fj = 0; fj < 2; ++fj) {
                const float* kp = kb + (size_t)(kt + fj * 16 + lrow) * D_HIDDEN + h0;
                const float4 k1 = *reinterpret_cast<const float4*>(kp);
                const float4 k2 = *reinterpret_cast<const float4*>(kp + 4);
                const float kf[8] = {k1.x, k1.y, k1.z, k1.w, k2.x, k2.y, k2.z, k2.w};
                #pragma unroll
                for (int i = 0; i < 8; ++i) bfrag[fj][i] = (short)f2bf(kf[i]);
            }
            #pragma unroll
            for (int fi = 0; fi < 2; ++fi)
                #pragma unroll
                for (int fj = 0; fj < 2; ++fj)
                    acc[fi][fj] = __builtin_amdgcn_mfma_f32_16x16x32_bf16(
                        afrag[fi], bfrag[fj], acc[fi][fj], 0, 0, 0);
        }

        #pragma unroll
        for (int fi = 0; fi < 2; ++fi)
            #pragma unroll
            for (int fj = 0; fj < 2; ++fj)
                #pragma unroll
                for (int j = 0; j < 4; ++j)
                    red[w][lane][fi * 8 + fj * 4 + j] = acc[fi][fj][j];
        __syncthreads();

        const float bd   = bdec[n];
        const int   outb = (b * NHEADS + n) * SEQ * SEQ;
        #pragma unroll
        for (int u = 0; u < 4; ++u) {
            const int j = w * 4 + u;
            const float s = (red[0][lane][j] + red[1][lane][j])
                          + (red[2][lane][j] + red[3][lane][j]);
            const int fi = j >> 3, fj = (j >> 2) & 1, jj = j & 3;
            const int row = qt + fi * 16 + (lane >> 4) * 4 + jj;
            const int col = kt + fj * 16 + (lane & 15);
            out[outb + row * SEQ + col] = s * 0.125f + bd;
        }
        return;
    }

    // ------------------------------- fires -------------------------------
    const int w  = t >> 6;
    const int l  = t & 63;
    const int g  = (bi - SCORE_BLOCKS) * 4 + w;           // 0..2047
    const int g7 = g >> 7;                                 // 0..15
    const int gk = g & 127;

    f32x4* out4 = reinterpret_cast<f32x4*>(out + FIRES_OFF - 1);  // 16B aligned
    float racc = 0.f;

    #pragma unroll 1
    for (int b = 0; b < 4; ++b) {
        // k-row constant across the 8 steps of this b
        const float* kr = kbuf + ((size_t)(b * SEQ) + gk) * D_HIDDEN;
        f32x4 kv[8];
        #pragma unroll
        for (int j = 0; j < 8; ++j)
            kv[j] = *reinterpret_cast<const f32x4*>(kr + 256 * j + 4 * l);
        float k3[8], k63[8];
        #pragma unroll
        for (int j = 0; j < 8; ++j) {
            k3[j]  = __shfl_up(kv[j][3], 1);
            k63[j] = __shfl(kv[j][3], 63);
        }

        #pragma unroll 1
        for (int ss = 0; ss < 8; ++ss) {
            const int s    = b * 8 + ss;
            const int R    = g + s * FIRES_WAVES;
            const int brow = s * 16 + g7;                  // R >> 7
            const float* qr = qbuf + (size_t)brow * D_HIDDEN;

            f32x4 qv[8];
            #pragma unroll
            for (int j = 0; j < 8; ++j)
                qv[j] = *reinterpret_cast<const f32x4*>(qr + 256 * j + 4 * l);

            float pm1 = 0.f;
            if (l == 0 && R > 0) {
                const int pbrow = (R - 1) >> 7;
                const int pb    = pbrow >> 7;
                const int pkrow = (pb << 7) + ((R - 1) & 127);
                pm1 = qbuf[(size_t)pbrow * D_HIDDEN + 2047]
                    * kbuf[(size_t)pkrow * D_HIDDEN + 2047];
            }

            float q3[8], q63[8];
            #pragma unroll
            for (int j = 0; j < 8; ++j) {
                q3[j]  = __shfl_up(qv[j][3], 1);
                q63[j] = __shfl(qv[j][3], 63);
            }

            #pragma unroll
            for (int j = 0; j < 8; ++j) {
                float p0;
                if (l == 0) {
                    p0 = (j == 0) ? pm1 : q63[j - 1] * k63[j - 1];
                } else {
                    p0 = q3[j] * k3[j];
                }
                const float p1 = qv[j][0] * kv[j][0];
                const float p2 = qv[j][1] * kv[j][1];
                const float p3 = qv[j][2] * kv[j][2];
                f32x4 f;
                f[0] = (p0 > 0.f) ? 1.f : 0.f;
                f[1] = (p1 > 0.f) ? 1.f : 0.f;
                f[2] = (p2 > 0.f) ? 1.f : 0.f;
                f[3] = (p3 > 0.f) ? 1.f : 0.f;
                if (R == 0 && j == 0 && l == 0) {
                    // protect out[REG_OFF]: scalar stores of f[1..3] only
                    out[FIRES_OFF + 0] = f[1];
                    out[FIRES_OFF + 1] = f[2];
                    out[FIRES_OFF + 2] = f[3];
                } else {
                    __builtin_nontemporal_store(f, &out4[(size_t)R * 512 + 64 * j + l]);
                }
                racc += (sqrtf(p0 + 1e-6f) + sqrtf(p1 + 1e-6f))
                      + (sqrtf(p2 + 1e-6f) + sqrtf(p3 + 1e-6f));
            }
        }
    }

    // exclude the fake first slot's sqrt (R=0, j=0, l=0, p0 = 0)
    if (g == 0 && l == 0) racc -= sqrtf(1e-6f);
    // global-last element (row 65535, h=2047)
    if (g == FIRES_WAVES - 1 && l == 0) {
        const float pv = qbuf[(size_t)511 * D_HIDDEN + 2047]
                       * kbuf[(size_t)511 * D_HIDDEN + 2047];
        out[(size_t)(FIRES_OFF - 1) + (size_t)NROWS_T * D_HIDDEN] = (pv > 0.f) ? 1.f : 0.f;
        racc += sqrtf(pv + 1e-6f);
    }

    #pragma unroll
    for (int off = 32; off > 0; off >>= 1) racc += __shfl_down(racc, off);
    if (l == 0) rs[w] = racc;
    __syncthreads();
    if (t == 0)
        atomicAdd(out + REG_OFF, ((rs[0] + rs[1]) + (rs[2] + rs[3])) * 1e-3f);
}

// ---------------------------------------------------------------------------
extern "C" void kernel_launch(void* const* d_in, const int* in_sizes, int n_in,
                              void* d_out, int out_size, void* d_ws, size_t ws_size,
                              hipStream_t stream) {
    const float* x  = (const float*)d_in[0];
    const float* WQ = (const float*)d_in[1];
    const float* WK = (const float*)d_in[2];
    const float* bQ = (const float*)d_in[3];
    const float* bK = (const float*)d_in[4];
    const float* Wd = (const float*)d_in[5];
    const float* bd = (const float*)d_in[6];
    float* out  = (float*)d_out;
    float* qbuf = (float*)d_ws;                                // 4 MB
    float* kbuf = qbuf + (size_t)MROWS * D_HIDDEN;             // 4 MB

    dim3 b256(256);

    enc_kernel<<<dim3(D_HIDDEN / 64, MROWS / 64, 2), b256, 0, stream>>>(
        x, WQ, WK, bQ, bK, qbuf, kbuf, out);

    main_kernel<<<dim3(SCORE_BLOCKS + FIRES_BLOCKS), b256, 0, stream>>>(
        qbuf, kbuf, Wd, bd, out);
}